// Round 11
// baseline (490.738 us; speedup 1.0000x reference)
//
#include <hip/hip_runtime.h>
#include <stdint.h>

// Problem dims (fixed by reference)
#define TOKENS 8192
#define DIN    4096
#define DOUT   4096

typedef short bf16x8 __attribute__((ext_vector_type(8)));   // 8 bf16 = 4 VGPRs
typedef float f32x16 __attribute__((ext_vector_type(16)));  // MFMA 32x32 accum
typedef int   i32x4  __attribute__((ext_vector_type(4)));   // NT-loadable int4
typedef float f32x4v __attribute__((ext_vector_type(4)));   // NT-loadable float4

// ---- fp32 -> bf16 round-to-nearest-even (inputs finite) ----
__device__ __forceinline__ unsigned short f2bf(float f) {
    union { float f; unsigned int u; } v; v.f = f;
    return (unsigned short)((v.u + 0x7fffu + ((v.u >> 16) & 1u)) >> 16);
}

// ---- ternary int {-1,0,1} -> bf16 bit pattern (2 selects, no float math) ----
__device__ __forceinline__ unsigned short tern2bf(int v) {
    return v == 0 ? (unsigned short)0u
                  : (v > 0 ? (unsigned short)0x3F80u : (unsigned short)0xBF80u);
}

// ---- async global->LDS, 16B/lane; LDS dest = wave-uniform base + lane*16 ----
__device__ __forceinline__ void gload_lds16(const unsigned short* g, unsigned short* l) {
    __builtin_amdgcn_global_load_lds(
        (const __attribute__((address_space(1))) unsigned int*)g,
        (__attribute__((address_space(3))) unsigned int*)l,
        16, 0, 0);
}

// ================= fused prologue (R9-verified): one kernel, two jobs =================
#define WBLKS 1024
#define XBLKS 2048

__global__ __launch_bounds__(256) void fused_cvt(
    const float* __restrict__ x, const int* __restrict__ W,
    unsigned short* __restrict__ xb, unsigned short* __restrict__ Wt) {
    __shared__ unsigned short lds[64][264];   // [n_local][k_local], pitch 264
    const int t = threadIdx.x;

    if (blockIdx.x < WBLKS) {
        // ---- W transpose: tile k0..k0+255 x n0..n0+63 ----
        const int b  = blockIdx.x;
        const int k0 = (b >> 6) * 256;        // 16 k-tiles
        const int n0 = (b & 63) * 64;         // 64 n-tiles
        const int kq = t >> 4;                // 0..15 (k quad group)
        const int nq = t & 15;                // 0..15 (n quad group)
#pragma unroll
        for (int it = 0; it < 4; ++it) {
            const int kb = it * 64 + kq * 4;  // k_local base (4 rows)
            const int* wp = &W[(size_t)(k0 + kb) * DOUT + n0 + nq * 4];
            i32x4 v0 = __builtin_nontemporal_load((const i32x4*)(wp));
            i32x4 v1 = __builtin_nontemporal_load((const i32x4*)(wp + DOUT));
            i32x4 v2 = __builtin_nontemporal_load((const i32x4*)(wp + 2 * DOUT));
            i32x4 v3 = __builtin_nontemporal_load((const i32x4*)(wp + 3 * DOUT));
            uint2 p;
            p.x = (unsigned)tern2bf(v0.x) | ((unsigned)tern2bf(v1.x) << 16);
            p.y = (unsigned)tern2bf(v2.x) | ((unsigned)tern2bf(v3.x) << 16);
            *(uint2*)&lds[nq * 4 + 0][kb] = p;
            p.x = (unsigned)tern2bf(v0.y) | ((unsigned)tern2bf(v1.y) << 16);
            p.y = (unsigned)tern2bf(v2.y) | ((unsigned)tern2bf(v3.y) << 16);
            *(uint2*)&lds[nq * 4 + 1][kb] = p;
            p.x = (unsigned)tern2bf(v0.z) | ((unsigned)tern2bf(v1.z) << 16);
            p.y = (unsigned)tern2bf(v2.z) | ((unsigned)tern2bf(v3.z) << 16);
            *(uint2*)&lds[nq * 4 + 2][kb] = p;
            p.x = (unsigned)tern2bf(v0.w) | ((unsigned)tern2bf(v1.w) << 16);
            p.y = (unsigned)tern2bf(v2.w) | ((unsigned)tern2bf(v3.w) << 16);
            *(uint2*)&lds[nq * 4 + 3][kb] = p;
        }
        __syncthreads();
        const int n = t >> 2;                 // 0..63
        const int s = t & 3;
        unsigned short* drow = Wt + (size_t)(n0 + n) * DIN + k0;
#pragma unroll
        for (int u = 0; u < 8; ++u) {
            const int k = u * 32 + s * 8;     // lanes 0-3 cover 64B contiguous
            *(uint4*)&drow[k] = *(const uint4*)&lds[n][k];
        }
    } else {
        // ---- x convert part: 8 chunks of 8 floats per thread ----
        const int b2 = blockIdx.x - WBLKS;    // 0..2047
        const int stride = XBLKS * 256;       // chunks per sweep
        int c = b2 * 256 + t;
        const f32x4v* x4 = (const f32x4v*)x;
        uint4* o = (uint4*)xb;                // 8 bf16 = 16B per chunk
#pragma unroll
        for (int j = 0; j < 8; ++j, c += stride) {
            f32x4v a = __builtin_nontemporal_load(&x4[2 * c]);
            f32x4v bvec = __builtin_nontemporal_load(&x4[2 * c + 1]);
            uint4 p;
            p.x = (unsigned)f2bf(a.x)    | ((unsigned)f2bf(a.y) << 16);
            p.y = (unsigned)f2bf(a.z)    | ((unsigned)f2bf(a.w) << 16);
            p.z = (unsigned)f2bf(bvec.x) | ((unsigned)f2bf(bvec.y) << 16);
            p.w = (unsigned)f2bf(bvec.z) | ((unsigned)f2bf(bvec.w) << 16);
            o[c] = p;
        }
    }
}

// ======== main GEMM: 256x256, BK=64, R10 pipeline, 32x32x16 MFMA (R11) ========
// Structure identical to R10 (race-free 1-barrier/phase, best measured 255us):
// same staging ledger, VM2@p2/p6, LGK4+SB0, read-ahead-1 A frags, B-burst at
// tile phase 0. ONLY the MFMA shape changes: 16x16x32 -> 32x32x16.
//   - wave tile 128x64 = 4 Mblk x 2 Nblk of 32x32; phase = 1 Mblk (8 MFMA).
//   - per-FLOP ceiling 2382 vs 2075 TF (+17%); half the MFMA instructions.
//   - A-frag: row=lane&31, k=(lane>>5)*8+e (gfx950 2xK analogy w/ verified
//     16x16); B-frag symmetric (col=lane&31) on W^T rows. C/D: col=lane&31,
//     row=(reg&3)+8*(reg>>2)+4*(lane>>5)  [m74/m101-verified].
//   - LDS quad swizzle unchanged: slot(row,q') holds global quad q'^(row&7);
//     read quad for ks: q' = (ks*2 + (lane>>5)) ^ (lane&7). Same 0-conflict
//     bank distribution as R10 (8 quads x 8 lanes).
// Ledger (unchanged): p0/p1 stage A@kt+64; p2/p3 stage B@kt+128 (VM2@p2);
// p4/p5 stage A@kt+128; p6/p7 stage B@kt+192 (VM2@p6). Never vmcnt 0 in loop.
#define BM 256
#define BN 256
#define BK 64

#define STAGE_A(bufi, h, kt)                                                \
    do {                                                                    \
        gload_lds16(gA + (size_t)((h) * 128) * DIN + (kt),                  \
                    &sA[bufi][(h) * 8192 + wave * 1024]);                   \
        gload_lds16(gA + (size_t)((h) * 128 + 8) * DIN + (kt),              \
                    &sA[bufi][(h) * 8192 + wave * 1024 + 512]);             \
    } while (0)

#define STAGE_B(bufi, h, kt)                                                \
    do {                                                                    \
        gload_lds16(gB + (size_t)((h) * 128) * DIN + (kt),                  \
                    &sB[bufi][(h) * 8192 + wave * 1024]);                   \
        gload_lds16(gB + (size_t)((h) * 128 + 8) * DIN + (kt),              \
                    &sB[bufi][(h) * 8192 + wave * 1024 + 512]);             \
    } while (0)

#define BAR  __builtin_amdgcn_s_barrier()
#define SB0  __builtin_amdgcn_sched_barrier(0)
#define VM4  asm volatile("s_waitcnt vmcnt(4)" ::: "memory")
#define VM2  asm volatile("s_waitcnt vmcnt(2)" ::: "memory")
#define VM0  asm volatile("s_waitcnt vmcnt(0)" ::: "memory")
#define LGK4 asm volatile("s_waitcnt lgkmcnt(4)" ::: "memory")
#define LGK0 asm volatile("s_waitcnt lgkmcnt(0)" ::: "memory")

// 8 ds_read_b128: all B-frags of LDS buffer BUF (2 Nblk x 4 ks, resident)
#define RD_B(BUF)                                                           \
    do {                                                                    \
        _Pragma("unroll") for (int nb = 0; nb < 2; ++nb)                    \
            _Pragma("unroll") for (int ks = 0; ks < 4; ++ks)                \
                bfr[nb][ks] =                                               \
                    *(const bf16x8*)&sB[BUF][rB + nb * 2048 + qe[ks]];      \
    } while (0)

// 4 ds_read_b128: A-frags (4 k-slices) of Mblk MQ, buffer BUF -> set AF
#define RD_A(AF, BUF, MQ)                                                   \
    do {                                                                    \
        _Pragma("unroll") for (int ks = 0; ks < 4; ++ks)                    \
            AF[ks] =                                                        \
                *(const bf16x8*)&sA[BUF][rA + (MQ) * 2048 + qe[ks]];        \
    } while (0)

// 8 MFMA 32x32x16: Mblk MQ from A-set AF + resident bfr
#define MM(AF, MQ)                                                          \
    do {                                                                    \
        __builtin_amdgcn_s_setprio(1);                                      \
        _Pragma("unroll") for (int ks = 0; ks < 4; ++ks)                    \
            _Pragma("unroll") for (int nb = 0; nb < 2; ++nb)                \
                acc[(MQ) * 2 + nb] =                                        \
                    __builtin_amdgcn_mfma_f32_32x32x16_bf16(                \
                        AF[ks], bfr[nb][ks], acc[(MQ) * 2 + nb], 0, 0, 0);  \
        __builtin_amdgcn_s_setprio(0);                                      \
    } while (0)

__global__ __launch_bounds__(512, 2) void gemm_bt(
    const unsigned short* __restrict__ A,   // [M][K] bf16
    const unsigned short* __restrict__ B,   // [N][K] bf16 (W transposed)
    float* __restrict__ C) {                // [M][N] fp32
    const int K = DIN, N = DOUT;

    __shared__ __align__(16) unsigned short sA[2][BM * BK];  // 2 x 32 KB
    __shared__ __align__(16) unsigned short sB[2][BN * BK];  // 2 x 32 KB

    const int tid  = threadIdx.x;
    const int wave = tid >> 6;
    const int lane = tid & 63;
    const int wm = wave >> 2;               // 0..1  (M)
    const int wn = wave & 3;                // 0..3  (N)

    // ---- T1: XCD-aware bijective block swizzle (512 wgs, 8 XCDs, 64/XCD) ----
    const int wg  = blockIdx.x + gridDim.x * blockIdx.y;   // hardware linear id
    const int xcd = wg & 7;
    const int idx = wg >> 3;                               // 0..63 within XCD
    const int bx  = (xcd & 1) * 8 + (idx & 7);             // 0..15  (N tiles)
    const int by  = (xcd >> 1) * 8 + (idx >> 3);           // 0..31  (M tiles)

    // ---- staging addressing: wave w stages rows 16w..16w+15 of each half ----
    const int lrow = lane >> 3;             // 0..7 row within 8-row chunk
    const int qsrc = (lane & 7) ^ lrow;     // pre-swizzled global k-quad
    const unsigned short* gA =
        A + (size_t)(by * BM + wave * 16 + lrow) * K + qsrc * 8;
    const unsigned short* gB =
        B + (size_t)(bx * BN + wave * 16 + lrow) * K + qsrc * 8;

    // ---- fragment read addressing (32x32 shape, swizzled ds_read) ----
    const int l31 = lane & 31;              // frag row/col
    const int hi  = lane >> 5;              // k-half selector
    const int x7  = lane & 7;               // row&7 of the frag row
    int qe[4];                              // swizzled quad offsets (elems)
#pragma unroll
    for (int ks = 0; ks < 4; ++ks)
        qe[ks] = (((ks * 2 + hi) ^ x7) << 3);
    const int rA = (wm * 128 + l31) << 6;   // *64 elems/row
    const int rB = (wn * 64 + l31) << 6;

    f32x16 acc[8];                          // 4 Mblk x 2 Nblk, 16 f32 each
#pragma unroll
    for (int i = 0; i < 8; ++i)
#pragma unroll
        for (int j = 0; j < 16; ++j)
            acc[i][j] = 0.f;
    bf16x8 bfr[2][4];     // B-frags: resident across a K-tile's 4 phases
    bf16x8 afA[4];        // A-frag ping (4 k-slices)
    bf16x8 afB[4];        // A-frag pong

    // ---- prologue: A0, B0, B1 (12 gloads); VM4 confirms A0,B0; B1 flies ----
    STAGE_A(0, 0, 0);
    STAGE_A(0, 1, 0);
    STAGE_B(0, 0, 0);
    STAGE_B(0, 1, 0);
    STAGE_B(1, 0, 64);
    STAGE_B(1, 1, 64);
    VM4;
    BAR;
    RD_A(afA, 0, 0);      // tile0 Mblk0 (consumed at first p0)

    // ---- main loop: 31 iters (tiles 0..61), 8 phases, 1 barrier each ----
    for (int kt = 0; kt + 256 <= K; kt += 128) {
        // p0: B0-burst (pinned first) + A Mblk1 ahead; MFMA Mblk0(buf0)
        RD_B(0); SB0; RD_A(afB, 0, 1);
        STAGE_A(1, 0, kt + 64);
        BAR; LGK4; SB0; MM(afA, 0);
        // p1
        RD_A(afA, 0, 2);
        STAGE_A(1, 1, kt + 64);
        BAR; LGK4; SB0; MM(afB, 1);
        // p2: VM2 confirms leftover B1 + A@kt+64 before BAR (p3 reads sA[1])
        RD_A(afB, 0, 3);
        STAGE_B(0, 0, kt + 128);
        VM2;
        BAR; LGK4; SB0; MM(afA, 2);
        // p3
        RD_A(afA, 1, 0);
        STAGE_B(0, 1, kt + 128);
        BAR; LGK4; SB0; MM(afB, 3);
        // p4: B1-burst + A1 Mblk1; MFMA Mblk0(buf1)
        RD_B(1); SB0; RD_A(afB, 1, 1);
        STAGE_A(0, 0, kt + 128);
        BAR; LGK4; SB0; MM(afA, 0);
        // p5
        RD_A(afA, 1, 2);
        STAGE_A(0, 1, kt + 128);
        BAR; LGK4; SB0; MM(afB, 1);
        // p6: VM2 confirms B@kt+128 + A@kt+128 before BAR (p7/next-p0 reads)
        RD_A(afB, 1, 3);
        STAGE_B(1, 0, kt + 192);
        VM2;
        BAR; LGK4; SB0; MM(afA, 2);
        // p7: read next tile0's Mblk0 from re-staged sA[0]
        RD_A(afA, 0, 0);
        STAGE_B(1, 1, kt + 192);
        BAR; LGK4; SB0; MM(afB, 3);
    }

    // ---- peeled tail: tiles 62 (buf0) and 63 (buf1) ----
    {
        RD_B(0); SB0; RD_A(afB, 0, 1);
        STAGE_A(1, 0, K - 64);
        BAR; LGK4; SB0; MM(afA, 0);

        RD_A(afA, 0, 2);
        STAGE_A(1, 1, K - 64);
        BAR; LGK4; SB0; MM(afB, 1);

        RD_A(afB, 0, 3);
        VM0;              // confirm B63 + A63 fully; no more stages
        BAR; LGK4; SB0; MM(afA, 2);

        RD_A(afA, 1, 0);
        BAR; LGK4; SB0; MM(afB, 3);

        RD_B(1); SB0; RD_A(afB, 1, 1);
        BAR; LGK4; SB0; MM(afA, 0);

        RD_A(afA, 1, 2);
        BAR; LGK4; SB0; MM(afB, 1);

        RD_A(afB, 1, 3);
        BAR; LGK4; SB0; MM(afA, 2);

        LGK0; SB0; MM(afB, 3);
    }

    // ---- epilogue: 32x32 C/D col=lane&31, row=(r&3)+8*(r>>2)+4*hi; NT ----
    float* Cw0 = C + (size_t)(by * BM + wm * 128) * N
                 + (size_t)(bx * BN + wn * 64 + l31);
    const int rbase = 4 * hi;
#pragma unroll
    for (int mq = 0; mq < 4; ++mq)
#pragma unroll
        for (int nb = 0; nb < 2; ++nb)
#pragma unroll
            for (int r = 0; r < 16; ++r) {
                const int row = mq * 32 + (r & 3) + 8 * (r >> 2) + rbase;
                __builtin_nontemporal_store(
                    acc[mq * 2 + nb][r], &Cw0[(size_t)row * N + nb * 32]);
            }
}

// ============ safety-net fallback if ws is too small (slow but correct) ============
__global__ void gemm_naive(const float* __restrict__ x, const int* __restrict__ W,
                           float* __restrict__ out) {
    int n = blockIdx.x * blockDim.x + threadIdx.x;
    int t = blockIdx.y;
    const float* xr = x + (size_t)t * DIN;
    float acc = 0.f;
    for (int k = 0; k < DIN; ++k)
        acc += xr[k] * (float)W[(size_t)k * DOUT + n];
    out[(size_t)t * DOUT + n] = acc;
}

extern "C" void kernel_launch(void* const* d_in, const int* in_sizes, int n_in,
                              void* d_out, int out_size, void* d_ws, size_t ws_size,
                              hipStream_t stream) {
    const float* x = (const float*)d_in[0];
    const int*   W = (const int*)d_in[1];
    float* out = (float*)d_out;

    const size_t xb_elems = (size_t)TOKENS * DIN;           // 64 MB bf16
    const size_t wt_elems = (size_t)DIN * DOUT;             // 32 MB bf16
    const size_t need = (xb_elems + wt_elems) * sizeof(unsigned short);

    if (ws_size < need) {   // should not happen; correctness safety net
        dim3 g(DOUT / 256, TOKENS);
        gemm_naive<<<g, 256, 0, stream>>>(x, W, out);
        return;
    }

    unsigned short* xb = (unsigned short*)d_ws;
    unsigned short* Wt = xb + xb_elems;

    fused_cvt<<<WBLKS + XBLKS, 256, 0, stream>>>(x, W, xb, Wt);

    dim3 grid(DOUT / BN, TOKENS / BM);   // (16, 32)
    gemm_bt<<<grid, 512, 0, stream>>>(xb, Wt, out);
}

// Round 12
// 469.310 us; speedup vs baseline: 1.0457x; 1.0457x over previous
//
#include <hip/hip_runtime.h>
#include <stdint.h>

// Problem dims (fixed by reference)
#define TOKENS 8192
#define DIN    4096
#define DOUT   4096

typedef short bf16x8 __attribute__((ext_vector_type(8)));  // 8 bf16 = 4 VGPRs
typedef float f32x4  __attribute__((ext_vector_type(4)));  // MFMA 16x16 accum
typedef int   i32x4  __attribute__((ext_vector_type(4)));  // NT-loadable int4
typedef float f32x4v __attribute__((ext_vector_type(4)));  // NT-loadable float4

// ---- fp32 -> bf16 round-to-nearest-even (inputs finite) ----
__device__ __forceinline__ unsigned short f2bf(float f) {
    union { float f; unsigned int u; } v; v.f = f;
    return (unsigned short)((v.u + 0x7fffu + ((v.u >> 16) & 1u)) >> 16);
}

// ---- ternary int {-1,0,1} -> bf16 bit pattern (2 selects, no float math) ----
__device__ __forceinline__ unsigned short tern2bf(int v) {
    return v == 0 ? (unsigned short)0u
                  : (v > 0 ? (unsigned short)0x3F80u : (unsigned short)0xBF80u);
}

// ---- async global->LDS, 16B/lane; LDS dest = wave-uniform base + lane*16 ----
__device__ __forceinline__ void gload_lds16(const unsigned short* g, unsigned short* l) {
    __builtin_amdgcn_global_load_lds(
        (const __attribute__((address_space(1))) unsigned int*)g,
        (__attribute__((address_space(3))) unsigned int*)l,
        16, 0, 0);
}

// ================= fused prologue (R9-verified): one kernel, two jobs =================
#define WBLKS 1024
#define XBLKS 2048

__global__ __launch_bounds__(256) void fused_cvt(
    const float* __restrict__ x, const int* __restrict__ W,
    unsigned short* __restrict__ xb, unsigned short* __restrict__ Wt) {
    __shared__ unsigned short lds[64][264];   // [n_local][k_local], pitch 264
    const int t = threadIdx.x;

    if (blockIdx.x < WBLKS) {
        // ---- W transpose: tile k0..k0+255 x n0..n0+63 ----
        const int b  = blockIdx.x;
        const int k0 = (b >> 6) * 256;        // 16 k-tiles
        const int n0 = (b & 63) * 64;         // 64 n-tiles
        const int kq = t >> 4;                // 0..15 (k quad group)
        const int nq = t & 15;                // 0..15 (n quad group)
#pragma unroll
        for (int it = 0; it < 4; ++it) {
            const int kb = it * 64 + kq * 4;  // k_local base (4 rows)
            const int* wp = &W[(size_t)(k0 + kb) * DOUT + n0 + nq * 4];
            i32x4 v0 = __builtin_nontemporal_load((const i32x4*)(wp));
            i32x4 v1 = __builtin_nontemporal_load((const i32x4*)(wp + DOUT));
            i32x4 v2 = __builtin_nontemporal_load((const i32x4*)(wp + 2 * DOUT));
            i32x4 v3 = __builtin_nontemporal_load((const i32x4*)(wp + 3 * DOUT));
            uint2 p;
            p.x = (unsigned)tern2bf(v0.x) | ((unsigned)tern2bf(v1.x) << 16);
            p.y = (unsigned)tern2bf(v2.x) | ((unsigned)tern2bf(v3.x) << 16);
            *(uint2*)&lds[nq * 4 + 0][kb] = p;
            p.x = (unsigned)tern2bf(v0.y) | ((unsigned)tern2bf(v1.y) << 16);
            p.y = (unsigned)tern2bf(v2.y) | ((unsigned)tern2bf(v3.y) << 16);
            *(uint2*)&lds[nq * 4 + 1][kb] = p;
            p.x = (unsigned)tern2bf(v0.z) | ((unsigned)tern2bf(v1.z) << 16);
            p.y = (unsigned)tern2bf(v2.z) | ((unsigned)tern2bf(v3.z) << 16);
            *(uint2*)&lds[nq * 4 + 2][kb] = p;
            p.x = (unsigned)tern2bf(v0.w) | ((unsigned)tern2bf(v1.w) << 16);
            p.y = (unsigned)tern2bf(v2.w) | ((unsigned)tern2bf(v3.w) << 16);
            *(uint2*)&lds[nq * 4 + 3][kb] = p;
        }
        __syncthreads();
        const int n = t >> 2;                 // 0..63
        const int s = t & 3;
        unsigned short* drow = Wt + (size_t)(n0 + n) * DIN + k0;
#pragma unroll
        for (int u = 0; u < 8; ++u) {
            const int k = u * 32 + s * 8;     // lanes 0-3 cover 64B contiguous
            *(uint4*)&drow[k] = *(const uint4*)&lds[n][k];
        }
    } else {
        // ---- x convert part: 8 chunks of 8 floats per thread ----
        const int b2 = blockIdx.x - WBLKS;    // 0..2047
        const int stride = XBLKS * 256;       // chunks per sweep
        int c = b2 * 256 + t;
        const f32x4v* x4 = (const f32x4v*)x;
        uint4* o = (uint4*)xb;                // 8 bf16 = 16B per chunk
#pragma unroll
        for (int j = 0; j < 8; ++j, c += stride) {
            f32x4v a = __builtin_nontemporal_load(&x4[2 * c]);
            f32x4v bvec = __builtin_nontemporal_load(&x4[2 * c + 1]);
            uint4 p;
            p.x = (unsigned)f2bf(a.x)    | ((unsigned)f2bf(a.y) << 16);
            p.y = (unsigned)f2bf(a.z)    | ((unsigned)f2bf(a.w) << 16);
            p.z = (unsigned)f2bf(bvec.x) | ((unsigned)f2bf(bvec.y) << 16);
            p.w = (unsigned)f2bf(bvec.z) | ((unsigned)f2bf(bvec.w) << 16);
            o[c] = p;
        }
    }
}

// ====== main GEMM: 256x256, BK=64, R10 ledger MERGED to 4 phases/iter (R12) ======
// 16x16x32 MFMA (R11's 32x32 regressed: bank conflicts). The only lever that has
// ever moved this GEMM is sync-op count (R3/R10: ~112 cyc/barrier). R12 halves
// it again: 4 phases x 32 MFMA, 4 barriers + 4 lgkm-waits + 2 vmcnt per iter.
//
// Phase = [same-phase reads: quad-pair A (8 b128) + B-burst (8) on pair 0]
//         [stage one full tile-operand (4 gloads)] [VM2 at P1/P3]
//         BAR; lgkmcnt(0); SB0; setprio(1); 32 MFMA; setprio(0)
//
// Ledger (same as R10 at full-tile granularity):
//   P0: stage A@kt+64->sA[1]    P1: stage B@kt+128->sB[0] + VM2
//   P2: stage A@kt+128->sA[0]   P3: stage B@kt+192->sB[1] + VM2
// VM2@P1 (leaves newest 2 of B@kt+128): confirms B@kt+64 + A@kt+64 in ALL waves
//   before BAR@P1 -> P2's sA[1]/sB[1] reads race-free.
// VM2@P3: confirms B@kt+128 + A@kt+128 -> next P0's sA[0]/sB[0] reads race-free.
// Never drains vmcnt to 0 in the loop.
// WAR: buffer X's last reads are issued at phase r and lgkm(0)-drained before
//   MFMA_r; the overwriting stage issues at r+1 after BAR_r, >= HBM latency
//   before its LDS write (same margin as R10, 3x benched).
// Tail (kt=K-128): P0 stages A@K-64; P1: VM0 (drain all); P2/P3 no stages.
#define BM 256
#define BN 256
#define BK 64

#define STAGE_A2(bufi, kt)                                                  \
    do {                                                                    \
        gload_lds16(gA + (kt), &sA[bufi][wave * 1024]);                     \
        gload_lds16(gA + (size_t)8 * DIN + (kt),                            \
                    &sA[bufi][wave * 1024 + 512]);                          \
        gload_lds16(gA + (size_t)128 * DIN + (kt),                          \
                    &sA[bufi][8192 + wave * 1024]);                         \
        gload_lds16(gA + (size_t)136 * DIN + (kt),                          \
                    &sA[bufi][8192 + wave * 1024 + 512]);                   \
    } while (0)

#define STAGE_B2(bufi, kt)                                                  \
    do {                                                                    \
        gload_lds16(gB + (kt), &sB[bufi][wave * 1024]);                     \
        gload_lds16(gB + (size_t)8 * DIN + (kt),                            \
                    &sB[bufi][wave * 1024 + 512]);                          \
        gload_lds16(gB + (size_t)128 * DIN + (kt),                          \
                    &sB[bufi][8192 + wave * 1024]);                         \
        gload_lds16(gB + (size_t)136 * DIN + (kt),                          \
                    &sB[bufi][8192 + wave * 1024 + 512]);                   \
    } while (0)

#define BAR  __builtin_amdgcn_s_barrier()
#define SB0  __builtin_amdgcn_sched_barrier(0)
#define VM4  asm volatile("s_waitcnt vmcnt(4)" ::: "memory")
#define VM2  asm volatile("s_waitcnt vmcnt(2)" ::: "memory")
#define VM0  asm volatile("s_waitcnt vmcnt(0)" ::: "memory")
#define LGK0 asm volatile("s_waitcnt lgkmcnt(0)" ::: "memory")

// One merged phase: quad pair QP (quadrants 2QP, 2QP+1) of buffer BUF.
// B-burst (8 b128) on QP==0; 8 A-reads (2 quadrants); 32 MFMA.
#define PH2(BUF, QP, STG, TAIL)                                             \
    {                                                                       \
        if ((QP) == 0) {                                                    \
            _Pragma("unroll") for (int ni = 0; ni < 4; ++ni) {              \
                bfr[ni][0] =                                                \
                    *(const bf16x8*)&sB[BUF][rowB + ni * 1024 + q80];       \
                bfr[ni][1] =                                                \
                    *(const bf16x8*)&sB[BUF][rowB + ni * 1024 + q81];       \
            }                                                               \
        }                                                                   \
        bf16x8 af[2][2][2]; /* [q][m2][ks] */                               \
        _Pragma("unroll") for (int q = 0; q < 2; ++q)                       \
            _Pragma("unroll") for (int m2 = 0; m2 < 2; ++m2) {              \
                const int mi = ((QP) * 2 + q) * 2 + m2;                     \
                af[q][m2][0] =                                              \
                    *(const bf16x8*)&sA[BUF][rowA + mi * 1024 + q80];       \
                af[q][m2][1] =                                              \
                    *(const bf16x8*)&sA[BUF][rowA + mi * 1024 + q81];       \
            }                                                               \
        STG;                                                                \
        TAIL;                                                               \
        BAR;                                                                \
        LGK0;                                                               \
        SB0;                                                                \
        __builtin_amdgcn_s_setprio(1);                                      \
        _Pragma("unroll") for (int q = 0; q < 2; ++q)                       \
            _Pragma("unroll") for (int ks = 0; ks < 2; ++ks)                \
                _Pragma("unroll") for (int m2 = 0; m2 < 2; ++m2)            \
                    _Pragma("unroll") for (int ni = 0; ni < 4; ++ni)        \
                        acc[((QP) * 2 + q) * 2 + m2][ni] =                  \
                            __builtin_amdgcn_mfma_f32_16x16x32_bf16(        \
                                af[q][m2][ks], bfr[ni][ks],                 \
                                acc[((QP) * 2 + q) * 2 + m2][ni], 0, 0, 0); \
        __builtin_amdgcn_s_setprio(0);                                      \
    }

__global__ __launch_bounds__(512, 2) void gemm_bt(
    const unsigned short* __restrict__ A,   // [M][K] bf16
    const unsigned short* __restrict__ B,   // [N][K] bf16 (W transposed)
    float* __restrict__ C) {                // [M][N] fp32
    const int K = DIN, N = DOUT;

    __shared__ __align__(16) unsigned short sA[2][BM * BK];  // 2 x 32 KB
    __shared__ __align__(16) unsigned short sB[2][BN * BK];  // 2 x 32 KB

    const int tid  = threadIdx.x;
    const int wave = tid >> 6;
    const int lane = tid & 63;
    const int wm = wave >> 2;               // 0..1  (M)
    const int wn = wave & 3;                // 0..3  (N)

    // ---- T1: XCD-aware bijective block swizzle (512 wgs, 8 XCDs, 64/XCD) ----
    const int wg  = blockIdx.x + gridDim.x * blockIdx.y;   // hardware linear id
    const int xcd = wg & 7;
    const int idx = wg >> 3;                               // 0..63 within XCD
    const int bx  = (xcd & 1) * 8 + (idx & 7);             // 0..15  (N tiles)
    const int by  = (xcd >> 1) * 8 + (idx >> 3);           // 0..31  (M tiles)

    // ---- staging addressing: wave w stages rows 16w..16w+15 of each half ----
    const int lrow = lane >> 3;             // 0..7 row within 8-row chunk
    const int qsrc = (lane & 7) ^ lrow;     // pre-swizzled global k-quad
    const unsigned short* gA =
        A + (size_t)(by * BM + wave * 16 + lrow) * K + qsrc * 8;
    const unsigned short* gB =
        B + (size_t)(bx * BN + wave * 16 + lrow) * K + qsrc * 8;

    // ---- fragment read addressing (16x16 shape, swizzled ds_read) ----
    const int mrow = lane & 15;
    const int kgrp = lane >> 4;             // 0..3
    const int xr   = lane & 7;              // = row&7 of the frag row
    const int q80  = ((kgrp ^ xr) << 3);        // ks=0 swizzled quad * 8
    const int q81  = (((4 | kgrp) ^ xr) << 3);  // ks=1
    const int rowA = (wm * 128 + mrow) << 6;    // *64 elems/row
    const int rowB = (wn * 64 + mrow) << 6;

    f32x4 acc[8][4];
#pragma unroll
    for (int i = 0; i < 8; ++i)
#pragma unroll
        for (int j = 0; j < 4; ++j) {
            f32x4 z = {0.f, 0.f, 0.f, 0.f};
            acc[i][j] = z;
        }
    bf16x8 bfr[4][2];     // B-frags: resident across a K-tile's 2 phases

    // ---- prologue: A0, B0, B1 (12 gloads); VM4 confirms A0,B0; B1 flies ----
    STAGE_A2(0, 0);
    STAGE_B2(0, 0);
    STAGE_B2(1, 64);
    VM4;
    BAR;

    // ---- main loop: 31 iters (tiles 0..61), 4 merged phases, 1 barrier each ----
    for (int kt = 0; kt + 256 <= K; kt += 128) {
        PH2(0, 0, STAGE_A2(1, kt + 64), )        // P0
        PH2(0, 1, STAGE_B2(0, kt + 128), VM2)    // P1
        PH2(1, 0, STAGE_A2(0, kt + 128), )       // P2
        PH2(1, 1, STAGE_B2(1, kt + 192), VM2)    // P3
    }

    // ---- peeled tail: tiles 62 (buf0) and 63 (buf1) ----
    PH2(0, 0, STAGE_A2(1, K - 64), )
    PH2(0, 1, , VM0)      // drain A@K-64 + leftover B@K-64: buf1 confirmed
    PH2(1, 0, , )
    PH2(1, 1, , )

    // ---- epilogue: C/D layout col=lane&15, row=(lane>>4)*4+reg; NT stores ----
    float* Cw = C + (size_t)(by * BM + wm * 128 + kgrp * 4) * N
                + (size_t)(bx * BN + wn * 64 + mrow);
#pragma unroll
    for (int mi = 0; mi < 8; ++mi)
#pragma unroll
        for (int ni = 0; ni < 4; ++ni)
#pragma unroll
            for (int r = 0; r < 4; ++r)
                __builtin_nontemporal_store(acc[mi][ni][r],
                                            &Cw[(size_t)(mi * 16 + r) * N + ni * 16]);
}

// ============ safety-net fallback if ws is too small (slow but correct) ============
__global__ void gemm_naive(const float* __restrict__ x, const int* __restrict__ W,
                           float* __restrict__ out) {
    int n = blockIdx.x * blockDim.x + threadIdx.x;
    int t = blockIdx.y;
    const float* xr = x + (size_t)t * DIN;
    float acc = 0.f;
    for (int k = 0; k < DIN; ++k)
        acc += xr[k] * (float)W[(size_t)k * DOUT + n];
    out[(size_t)t * DOUT + n] = acc;
}

extern "C" void kernel_launch(void* const* d_in, const int* in_sizes, int n_in,
                              void* d_out, int out_size, void* d_ws, size_t ws_size,
                              hipStream_t stream) {
    const float* x = (const float*)d_in[0];
    const int*   W = (const int*)d_in[1];
    float* out = (float*)d_out;

    const size_t xb_elems = (size_t)TOKENS * DIN;           // 64 MB bf16
    const size_t wt_elems = (size_t)DIN * DOUT;             // 32 MB bf16
    const size_t need = (xb_elems + wt_elems) * sizeof(unsigned short);

    if (ws_size < need) {   // should not happen; correctness safety net
        dim3 g(DOUT / 256, TOKENS);
        gemm_naive<<<g, 256, 0, stream>>>(x, W, out);
        return;
    }

    unsigned short* xb = (unsigned short*)d_ws;
    unsigned short* Wt = xb + xb_elems;

    fused_cvt<<<WBLKS + XBLKS, 256, 0, stream>>>(x, W, xb, Wt);

    dim3 grid(DOUT / BN, TOKENS / BM);   // (16, 32)
    gemm_bt<<<grid, 512, 0, stream>>>(xb, Wt, out);
}

// Round 13
// 465.215 us; speedup vs baseline: 1.0549x; 1.0088x over previous
//
#include <hip/hip_runtime.h>
#include <stdint.h>

// Problem dims (fixed by reference)
#define TOKENS 8192
#define DIN    4096
#define DOUT   4096

typedef short bf16x8 __attribute__((ext_vector_type(8)));  // 8 bf16 = 4 VGPRs
typedef float f32x4  __attribute__((ext_vector_type(4)));  // MFMA 16x16 accum
typedef int   i32x4  __attribute__((ext_vector_type(4)));  // NT-loadable int4
typedef float f32x4v __attribute__((ext_vector_type(4)));  // NT-loadable float4

// ---- fp32 -> bf16 round-to-nearest-even (inputs finite) ----
__device__ __forceinline__ unsigned short f2bf(float f) {
    union { float f; unsigned int u; } v; v.f = f;
    return (unsigned short)((v.u + 0x7fffu + ((v.u >> 16) & 1u)) >> 16);
}

// ---- ternary int {-1,0,1} -> bf16 bit pattern (2 selects, no float math) ----
__device__ __forceinline__ unsigned short tern2bf(int v) {
    return v == 0 ? (unsigned short)0u
                  : (v > 0 ? (unsigned short)0x3F80u : (unsigned short)0xBF80u);
}

// ---- async global->LDS, 16B/lane; LDS dest = wave-uniform base + lane*16 ----
__device__ __forceinline__ void gload_lds16(const unsigned short* g, unsigned short* l) {
    __builtin_amdgcn_global_load_lds(
        (const __attribute__((address_space(1))) unsigned int*)g,
        (__attribute__((address_space(3))) unsigned int*)l,
        16, 0, 0);
}

// ================= fused prologue (R9-verified): one kernel, two jobs =================
#define WBLKS 1024
#define XBLKS 2048

__global__ __launch_bounds__(256) void fused_cvt(
    const float* __restrict__ x, const int* __restrict__ W,
    unsigned short* __restrict__ xb, unsigned short* __restrict__ Wt) {
    __shared__ unsigned short lds[64][264];   // [n_local][k_local], pitch 264
    const int t = threadIdx.x;

    if (blockIdx.x < WBLKS) {
        // ---- W transpose: tile k0..k0+255 x n0..n0+63 ----
        const int b  = blockIdx.x;
        const int k0 = (b >> 6) * 256;        // 16 k-tiles
        const int n0 = (b & 63) * 64;         // 64 n-tiles
        const int kq = t >> 4;                // 0..15 (k quad group)
        const int nq = t & 15;                // 0..15 (n quad group)
#pragma unroll
        for (int it = 0; it < 4; ++it) {
            const int kb = it * 64 + kq * 4;  // k_local base (4 rows)
            const int* wp = &W[(size_t)(k0 + kb) * DOUT + n0 + nq * 4];
            i32x4 v0 = __builtin_nontemporal_load((const i32x4*)(wp));
            i32x4 v1 = __builtin_nontemporal_load((const i32x4*)(wp + DOUT));
            i32x4 v2 = __builtin_nontemporal_load((const i32x4*)(wp + 2 * DOUT));
            i32x4 v3 = __builtin_nontemporal_load((const i32x4*)(wp + 3 * DOUT));
            uint2 p;
            p.x = (unsigned)tern2bf(v0.x) | ((unsigned)tern2bf(v1.x) << 16);
            p.y = (unsigned)tern2bf(v2.x) | ((unsigned)tern2bf(v3.x) << 16);
            *(uint2*)&lds[nq * 4 + 0][kb] = p;
            p.x = (unsigned)tern2bf(v0.y) | ((unsigned)tern2bf(v1.y) << 16);
            p.y = (unsigned)tern2bf(v2.y) | ((unsigned)tern2bf(v3.y) << 16);
            *(uint2*)&lds[nq * 4 + 1][kb] = p;
            p.x = (unsigned)tern2bf(v0.z) | ((unsigned)tern2bf(v1.z) << 16);
            p.y = (unsigned)tern2bf(v2.z) | ((unsigned)tern2bf(v3.z) << 16);
            *(uint2*)&lds[nq * 4 + 2][kb] = p;
            p.x = (unsigned)tern2bf(v0.w) | ((unsigned)tern2bf(v1.w) << 16);
            p.y = (unsigned)tern2bf(v2.w) | ((unsigned)tern2bf(v3.w) << 16);
            *(uint2*)&lds[nq * 4 + 3][kb] = p;
        }
        __syncthreads();
        const int n = t >> 2;                 // 0..63
        const int s = t & 3;
        unsigned short* drow = Wt + (size_t)(n0 + n) * DIN + k0;
#pragma unroll
        for (int u = 0; u < 8; ++u) {
            const int k = u * 32 + s * 8;     // lanes 0-3 cover 64B contiguous
            *(uint4*)&drow[k] = *(const uint4*)&lds[n][k];
        }
    } else {
        // ---- x convert part: 8 chunks of 8 floats per thread ----
        const int b2 = blockIdx.x - WBLKS;    // 0..2047
        const int stride = XBLKS * 256;       // chunks per sweep
        int c = b2 * 256 + t;
        const f32x4v* x4 = (const f32x4v*)x;
        uint4* o = (uint4*)xb;                // 8 bf16 = 16B per chunk
#pragma unroll
        for (int j = 0; j < 8; ++j, c += stride) {
            f32x4v a = __builtin_nontemporal_load(&x4[2 * c]);
            f32x4v bvec = __builtin_nontemporal_load(&x4[2 * c + 1]);
            uint4 p;
            p.x = (unsigned)f2bf(a.x)    | ((unsigned)f2bf(a.y) << 16);
            p.y = (unsigned)f2bf(a.z)    | ((unsigned)f2bf(a.w) << 16);
            p.z = (unsigned)f2bf(bvec.x) | ((unsigned)f2bf(bvec.y) << 16);
            p.w = (unsigned)f2bf(bvec.z) | ((unsigned)f2bf(bvec.w) << 16);
            o[c] = p;
        }
    }
}

// ========= main GEMM: 256x256, BK=64, 1-barrier/phase race-free pipeline =========
// R13 = R10 (session-best gemm, 255 us, race-audited) with ONE change:
// plain C stores (no nontemporal) so L2 write-combines the 64B line-halves
// (R10 NT wrote 170 MB vs 128 MB ideal; R11's 32-contig layout showed 131).
//
// Phase: [reads (next-phase A-quad; +B-burst at p0/p4)] [stage half-tile]
//        [VM2 at p2/p6] BAR LGK4 SB0 setprio(1) 16xMFMA setprio(0)
// Stage ledger per iter (tiles t0=buf0@kt, t1=buf1@kt+64):
//   p0/p1: A@kt+64 -> sA[1]     p2/p3: B@kt+128 -> sB[0]
//   p4/p5: A@kt+128 -> sA[0]    p6/p7: B@kt+192 -> sB[1]
// VM2@p2: confirms leftover B1 + A@kt+64 cross-wave before p3's sA[1] read.
// VM2@p6: confirms B@kt+128 + A@kt+128 before p7/next-p0 reads. Never 0 in loop.
// WAR: last reads of a buffer drain via LGK4 before the barrier preceding the
// overwriting stage issue. LGK4 = "all but my 4 newest" (in-order DS) = this
// phase's MFMA operands complete; B-burst pinned before A-reads by SB0.
#define BM 256
#define BN 256
#define BK 64

#define STAGE_A(bufi, h, kt)                                                \
    do {                                                                    \
        gload_lds16(gA + (size_t)((h) * 128) * DIN + (kt),                  \
                    &sA[bufi][(h) * 8192 + wave * 1024]);                   \
        gload_lds16(gA + (size_t)((h) * 128 + 8) * DIN + (kt),              \
                    &sA[bufi][(h) * 8192 + wave * 1024 + 512]);             \
    } while (0)

#define STAGE_B(bufi, h, kt)                                                \
    do {                                                                    \
        gload_lds16(gB + (size_t)((h) * 128) * DIN + (kt),                  \
                    &sB[bufi][(h) * 8192 + wave * 1024]);                   \
        gload_lds16(gB + (size_t)((h) * 128 + 8) * DIN + (kt),              \
                    &sB[bufi][(h) * 8192 + wave * 1024 + 512]);             \
    } while (0)

#define BAR  __builtin_amdgcn_s_barrier()
#define SB0  __builtin_amdgcn_sched_barrier(0)
#define VM4  asm volatile("s_waitcnt vmcnt(4)" ::: "memory")
#define VM2  asm volatile("s_waitcnt vmcnt(2)" ::: "memory")
#define VM0  asm volatile("s_waitcnt vmcnt(0)" ::: "memory")
#define LGK4 asm volatile("s_waitcnt lgkmcnt(4)" ::: "memory")
#define LGK0 asm volatile("s_waitcnt lgkmcnt(0)" ::: "memory")

// 8 ds_read_b128: all B-frags of LDS buffer BUF (resident across 4 phases)
#define RD_B(BUF)                                                           \
    do {                                                                    \
        _Pragma("unroll") for (int ni = 0; ni < 4; ++ni) {                  \
            bfr[ni][0] = *(const bf16x8*)&sB[BUF][rowB + ni * 1024 + q80];  \
            bfr[ni][1] = *(const bf16x8*)&sB[BUF][rowB + ni * 1024 + q81];  \
        }                                                                   \
    } while (0)

// 4 ds_read_b128: A-frags, quadrant QD of buffer BUF -> register set AF
#define RD_A(AF, BUF, QD)                                                   \
    do {                                                                    \
        _Pragma("unroll") for (int m2 = 0; m2 < 2; ++m2) {                  \
            AF[m2][0] =                                                     \
                *(const bf16x8*)&sA[BUF][rowA + ((QD)*2 + m2) * 1024 + q80];\
            AF[m2][1] =                                                     \
                *(const bf16x8*)&sA[BUF][rowA + ((QD)*2 + m2) * 1024 + q81];\
        }                                                                   \
    } while (0)

// 16 MFMA: quadrant QD from A-set AF + resident bfr
#define MM(AF, QD)                                                          \
    do {                                                                    \
        __builtin_amdgcn_s_setprio(1);                                      \
        _Pragma("unroll") for (int ks = 0; ks < 2; ++ks)                    \
            _Pragma("unroll") for (int m2 = 0; m2 < 2; ++m2)                \
                _Pragma("unroll") for (int ni = 0; ni < 4; ++ni)            \
                    acc[(QD)*2 + m2][ni] =                                  \
                        __builtin_amdgcn_mfma_f32_16x16x32_bf16(            \
                            AF[m2][ks], bfr[ni][ks],                        \
                            acc[(QD)*2 + m2][ni], 0, 0, 0);                 \
        __builtin_amdgcn_s_setprio(0);                                      \
    } while (0)

__global__ __launch_bounds__(512, 2) void gemm_bt(
    const unsigned short* __restrict__ A,   // [M][K] bf16
    const unsigned short* __restrict__ B,   // [N][K] bf16 (W transposed)
    float* __restrict__ C) {                // [M][N] fp32
    const int K = DIN, N = DOUT;

    __shared__ __align__(16) unsigned short sA[2][BM * BK];  // 2 x 32 KB
    __shared__ __align__(16) unsigned short sB[2][BN * BK];  // 2 x 32 KB

    const int tid  = threadIdx.x;
    const int wave = tid >> 6;
    const int lane = tid & 63;
    const int wm = wave >> 2;               // 0..1  (M)
    const int wn = wave & 3;                // 0..3  (N)

    // ---- T1: XCD-aware bijective block swizzle (512 wgs, 8 XCDs, 64/XCD) ----
    const int wg  = blockIdx.x + gridDim.x * blockIdx.y;   // hardware linear id
    const int xcd = wg & 7;
    const int idx = wg >> 3;                               // 0..63 within XCD
    const int bx  = (xcd & 1) * 8 + (idx & 7);             // 0..15  (N tiles)
    const int by  = (xcd >> 1) * 8 + (idx >> 3);           // 0..31  (M tiles)

    // ---- staging addressing: wave w stages rows 16w..16w+15 of each half ----
    const int lrow = lane >> 3;             // 0..7 row within 8-row chunk
    const int qsrc = (lane & 7) ^ lrow;     // pre-swizzled global k-quad
    const unsigned short* gA =
        A + (size_t)(by * BM + wave * 16 + lrow) * K + qsrc * 8;
    const unsigned short* gB =
        B + (size_t)(bx * BN + wave * 16 + lrow) * K + qsrc * 8;

    // ---- fragment read addressing (swizzled ds_read) ----
    const int mrow = lane & 15;
    const int kgrp = lane >> 4;             // 0..3
    const int xr   = lane & 7;              // = row&7 of the frag row
    const int q80  = ((kgrp ^ xr) << 3);        // ks=0 swizzled quad * 8
    const int q81  = (((4 | kgrp) ^ xr) << 3);  // ks=1
    const int rowA = (wm * 128 + mrow) << 6;    // *64 elems/row
    const int rowB = (wn * 64 + mrow) << 6;

    f32x4 acc[8][4];
#pragma unroll
    for (int i = 0; i < 8; ++i)
#pragma unroll
        for (int j = 0; j < 4; ++j) {
            f32x4 z = {0.f, 0.f, 0.f, 0.f};
            acc[i][j] = z;
        }
    bf16x8 bfr[4][2];     // B-frags: resident across a K-tile's 4 phases
    bf16x8 afA[2][2];     // A-frag ping
    bf16x8 afB[2][2];     // A-frag pong

    // ---- prologue: A0, B0, B1 (12 gloads); VM4 confirms A0,B0; B1 flies ----
    STAGE_A(0, 0, 0);
    STAGE_A(0, 1, 0);
    STAGE_B(0, 0, 0);
    STAGE_B(0, 1, 0);
    STAGE_B(1, 0, 64);
    STAGE_B(1, 1, 64);
    VM4;
    BAR;
    RD_A(afA, 0, 0);      // tile0 Q0 (consumed at first p0)

    // ---- main loop: 31 iters (tiles 0..61), 8 phases, 1 barrier each ----
    for (int kt = 0; kt + 256 <= K; kt += 128) {
        // p0: B0-burst (pinned first) + A0Q1 ahead; MFMA Q0(buf0)
        RD_B(0); SB0; RD_A(afB, 0, 1);
        STAGE_A(1, 0, kt + 64);
        BAR; LGK4; SB0; MM(afA, 0);
        // p1
        RD_A(afA, 0, 2);
        STAGE_A(1, 1, kt + 64);
        BAR; LGK4; SB0; MM(afB, 1);
        // p2: VM2 confirms leftover B1 + A@kt+64 before BAR (p3 reads sA[1])
        RD_A(afB, 0, 3);
        STAGE_B(0, 0, kt + 128);
        VM2;
        BAR; LGK4; SB0; MM(afA, 2);
        // p3
        RD_A(afA, 1, 0);
        STAGE_B(0, 1, kt + 128);
        BAR; LGK4; SB0; MM(afB, 3);
        // p4: B1-burst + A1Q1; MFMA Q0(buf1)
        RD_B(1); SB0; RD_A(afB, 1, 1);
        STAGE_A(0, 0, kt + 128);
        BAR; LGK4; SB0; MM(afA, 0);
        // p5
        RD_A(afA, 1, 2);
        STAGE_A(0, 1, kt + 128);
        BAR; LGK4; SB0; MM(afB, 1);
        // p6: VM2 confirms B@kt+128 + A@kt+128 before BAR (p7/next-p0 reads)
        RD_A(afB, 1, 3);
        STAGE_B(1, 0, kt + 192);
        VM2;
        BAR; LGK4; SB0; MM(afA, 2);
        // p7: read next tile0's Q0 from re-staged sA[0]
        RD_A(afA, 0, 0);
        STAGE_B(1, 1, kt + 192);
        BAR; LGK4; SB0; MM(afB, 3);
    }

    // ---- peeled tail: tiles 62 (buf0) and 63 (buf1) ----
    {
        RD_B(0); SB0; RD_A(afB, 0, 1);
        STAGE_A(1, 0, K - 64);
        BAR; LGK4; SB0; MM(afA, 0);

        RD_A(afA, 0, 2);
        STAGE_A(1, 1, K - 64);
        BAR; LGK4; SB0; MM(afB, 1);

        RD_A(afB, 0, 3);
        VM0;              // confirm B63 + A63 fully; no more stages
        BAR; LGK4; SB0; MM(afA, 2);

        RD_A(afA, 1, 0);
        BAR; LGK4; SB0; MM(afB, 3);

        RD_B(1); SB0; RD_A(afB, 1, 1);
        BAR; LGK4; SB0; MM(afA, 0);

        RD_A(afA, 1, 2);
        BAR; LGK4; SB0; MM(afB, 1);

        RD_A(afB, 1, 3);
        BAR; LGK4; SB0; MM(afA, 2);

        LGK0; SB0; MM(afB, 3);
    }

    // ---- epilogue: C/D layout col=lane&15, row=(lane>>4)*4+reg ----
    // R13: PLAIN stores (no NT) -> L2 merges the 64B line-halves written by
    // adjacent ni iterations into full 128B lines before writeback.
    float* Cw = C + (size_t)(by * BM + wm * 128 + kgrp * 4) * N
                + (size_t)(bx * BN + wn * 64 + mrow);
#pragma unroll
    for (int mi = 0; mi < 8; ++mi)
#pragma unroll
        for (int ni = 0; ni < 4; ++ni)
#pragma unroll
            for (int r = 0; r < 4; ++r)
                Cw[(size_t)(mi * 16 + r) * N + ni * 16] = acc[mi][ni][r];
}

// ============ safety-net fallback if ws is too small (slow but correct) ============
__global__ void gemm_naive(const float* __restrict__ x, const int* __restrict__ W,
                           float* __restrict__ out) {
    int n = blockIdx.x * blockDim.x + threadIdx.x;
    int t = blockIdx.y;
    const float* xr = x + (size_t)t * DIN;
    float acc = 0.f;
    for (int k = 0; k < DIN; ++k)
        acc += xr[k] * (float)W[(size_t)k * DOUT + n];
    out[(size_t)t * DOUT + n] = acc;
}

extern "C" void kernel_launch(void* const* d_in, const int* in_sizes, int n_in,
                              void* d_out, int out_size, void* d_ws, size_t ws_size,
                              hipStream_t stream) {
    const float* x = (const float*)d_in[0];
    const int*   W = (const int*)d_in[1];
    float* out = (float*)d_out;

    const size_t xb_elems = (size_t)TOKENS * DIN;           // 64 MB bf16
    const size_t wt_elems = (size_t)DIN * DOUT;             // 32 MB bf16
    const size_t need = (xb_elems + wt_elems) * sizeof(unsigned short);

    if (ws_size < need) {   // should not happen; correctness safety net
        dim3 g(DOUT / 256, TOKENS);
        gemm_naive<<<g, 256, 0, stream>>>(x, W, out);
        return;
    }

    unsigned short* xb = (unsigned short*)d_ws;
    unsigned short* Wt = xb + xb_elems;

    fused_cvt<<<WBLKS + XBLKS, 256, 0, stream>>>(x, W, xb, Wt);

    dim3 grid(DOUT / BN, TOKENS / BM);   // (16, 32)
    gemm_bt<<<grid, 512, 0, stream>>>(xb, Wt, out);
}

// Round 14
// 460.054 us; speedup vs baseline: 1.0667x; 1.0112x over previous
//
#include <hip/hip_runtime.h>
#include <stdint.h>

// Problem dims (fixed by reference)
#define TOKENS 8192
#define DIN    4096
#define DOUT   4096

typedef short bf16x8 __attribute__((ext_vector_type(8)));  // 8 bf16 = 4 VGPRs
typedef float f32x4  __attribute__((ext_vector_type(4)));  // MFMA 16x16 accum
typedef int   i32x4  __attribute__((ext_vector_type(4)));  // NT-loadable int4
typedef float f32x4v __attribute__((ext_vector_type(4)));  // NT-loadable float4

// ---- fp32 -> bf16 round-to-nearest-even (inputs finite) ----
__device__ __forceinline__ unsigned short f2bf(float f) {
    union { float f; unsigned int u; } v; v.f = f;
    return (unsigned short)((v.u + 0x7fffu + ((v.u >> 16) & 1u)) >> 16);
}

// ---- ternary int {-1,0,1} -> bf16 bit pattern (2 selects, no float math) ----
__device__ __forceinline__ unsigned short tern2bf(int v) {
    return v == 0 ? (unsigned short)0u
                  : (v > 0 ? (unsigned short)0x3F80u : (unsigned short)0xBF80u);
}

// ---- async global->LDS, 16B/lane; LDS dest = wave-uniform base + lane*16 ----
__device__ __forceinline__ void gload_lds16(const unsigned short* g, unsigned short* l) {
    __builtin_amdgcn_global_load_lds(
        (const __attribute__((address_space(1))) unsigned int*)g,
        (__attribute__((address_space(3))) unsigned int*)l,
        16, 0, 0);
}

// ================= fused prologue (R9-verified): one kernel, two jobs =================
#define WBLKS 1024
#define XBLKS 2048

__global__ __launch_bounds__(256) void fused_cvt(
    const float* __restrict__ x, const int* __restrict__ W,
    unsigned short* __restrict__ xb, unsigned short* __restrict__ Wt) {
    __shared__ unsigned short lds[64][264];   // [n_local][k_local], pitch 264
    const int t = threadIdx.x;

    if (blockIdx.x < WBLKS) {
        // ---- W transpose: tile k0..k0+255 x n0..n0+63 ----
        const int b  = blockIdx.x;
        const int k0 = (b >> 6) * 256;        // 16 k-tiles
        const int n0 = (b & 63) * 64;         // 64 n-tiles
        const int kq = t >> 4;                // 0..15 (k quad group)
        const int nq = t & 15;                // 0..15 (n quad group)
#pragma unroll
        for (int it = 0; it < 4; ++it) {
            const int kb = it * 64 + kq * 4;  // k_local base (4 rows)
            const int* wp = &W[(size_t)(k0 + kb) * DOUT + n0 + nq * 4];
            i32x4 v0 = __builtin_nontemporal_load((const i32x4*)(wp));
            i32x4 v1 = __builtin_nontemporal_load((const i32x4*)(wp + DOUT));
            i32x4 v2 = __builtin_nontemporal_load((const i32x4*)(wp + 2 * DOUT));
            i32x4 v3 = __builtin_nontemporal_load((const i32x4*)(wp + 3 * DOUT));
            uint2 p;
            p.x = (unsigned)tern2bf(v0.x) | ((unsigned)tern2bf(v1.x) << 16);
            p.y = (unsigned)tern2bf(v2.x) | ((unsigned)tern2bf(v3.x) << 16);
            *(uint2*)&lds[nq * 4 + 0][kb] = p;
            p.x = (unsigned)tern2bf(v0.y) | ((unsigned)tern2bf(v1.y) << 16);
            p.y = (unsigned)tern2bf(v2.y) | ((unsigned)tern2bf(v3.y) << 16);
            *(uint2*)&lds[nq * 4 + 1][kb] = p;
            p.x = (unsigned)tern2bf(v0.z) | ((unsigned)tern2bf(v1.z) << 16);
            p.y = (unsigned)tern2bf(v2.z) | ((unsigned)tern2bf(v3.z) << 16);
            *(uint2*)&lds[nq * 4 + 2][kb] = p;
            p.x = (unsigned)tern2bf(v0.w) | ((unsigned)tern2bf(v1.w) << 16);
            p.y = (unsigned)tern2bf(v2.w) | ((unsigned)tern2bf(v3.w) << 16);
            *(uint2*)&lds[nq * 4 + 3][kb] = p;
        }
        __syncthreads();
        const int n = t >> 2;                 // 0..63
        const int s = t & 3;
        unsigned short* drow = Wt + (size_t)(n0 + n) * DIN + k0;
#pragma unroll
        for (int u = 0; u < 8; ++u) {
            const int k = u * 32 + s * 8;     // lanes 0-3 cover 64B contiguous
            *(uint4*)&drow[k] = *(const uint4*)&lds[n][k];
        }
    } else {
        // ---- x convert part: 8 chunks of 8 floats per thread ----
        const int b2 = blockIdx.x - WBLKS;    // 0..2047
        const int stride = XBLKS * 256;       // chunks per sweep
        int c = b2 * 256 + t;
        const f32x4v* x4 = (const f32x4v*)x;
        uint4* o = (uint4*)xb;                // 8 bf16 = 16B per chunk
#pragma unroll
        for (int j = 0; j < 8; ++j, c += stride) {
            f32x4v a = __builtin_nontemporal_load(&x4[2 * c]);
            f32x4v bvec = __builtin_nontemporal_load(&x4[2 * c + 1]);
            uint4 p;
            p.x = (unsigned)f2bf(a.x)    | ((unsigned)f2bf(a.y) << 16);
            p.y = (unsigned)f2bf(a.z)    | ((unsigned)f2bf(a.w) << 16);
            p.z = (unsigned)f2bf(bvec.x) | ((unsigned)f2bf(bvec.y) << 16);
            p.w = (unsigned)f2bf(bvec.z) | ((unsigned)f2bf(bvec.w) << 16);
            o[c] = p;
        }
    }
}

// ====== main GEMM: 256x256, BK=64, 4 merged phases + COUNTED waits (R14) ======
// R14 = R13's pipeline with quadrant-pairs merged: 4 barriers/iter (was 8),
// keeping counted lgkm (R12's failure was lgkmcnt(0) re-serialization).
// Phase = [reads up-front, SB0-pinned] [stage 1 full operand (4 gloads)]
//         [VM2 at P1/P3] BAR; LGK4; 16 MFMA; LGK0; 16 MFMA
// First-use quads read same-phase AFTER the previous phase's VM2+BAR (no
// cross-boundary read-ahead -> R3's race class structurally excluded).
//
// Ledger (R12-benched, full-operand stages):
//   P0: stage A@kt+64->sA[1]    P1: stage B@kt+128->sB[0] + VM2
//   P2: stage A@kt+128->sA[0]   P3: stage B@kt+192->sB[1] + VM2
// FIFO: entering P0 = 4 outstanding (B@kt+64 tail). P1's VM2 (10->2) confirms
// B@kt+64 + A@kt+64 in ALL waves before BAR -> P2's buf1 reads race-free.
// P3's VM2 confirms B@kt+128 + A@kt+128 -> next P0's buf0 reads race-free.
// Never drains vmcnt to 0 in the loop.
// LGK math (in-order DS): P0 issues 16 reads [A-Q0(4), B(8), A-Q1(4)]:
//   LGK4 allows newest 4 (Q1) -> Q0+B done -> MFMA Q0; LGK0 -> MFMA Q1.
// P1 issues 8 [Q2(4), Q3(4)]: LGK4 -> MFMA Q2; LGK0 -> MFMA Q3.
// WAR: reads of a buffer are lgkm-drained within their phase (LGK0 before the
// 2nd cluster) >= 1 barrier + ~900cy HBM latency before the overwrite lands.
#define BM 256
#define BN 256
#define BK 64

#define STAGE_A2(bufi, kt)                                                  \
    do {                                                                    \
        gload_lds16(gA + (kt), &sA[bufi][wave * 1024]);                     \
        gload_lds16(gA + (size_t)8 * DIN + (kt),                            \
                    &sA[bufi][wave * 1024 + 512]);                          \
        gload_lds16(gA + (size_t)128 * DIN + (kt),                          \
                    &sA[bufi][8192 + wave * 1024]);                         \
        gload_lds16(gA + (size_t)136 * DIN + (kt),                          \
                    &sA[bufi][8192 + wave * 1024 + 512]);                   \
    } while (0)

#define STAGE_B2(bufi, kt)                                                  \
    do {                                                                    \
        gload_lds16(gB + (kt), &sB[bufi][wave * 1024]);                     \
        gload_lds16(gB + (size_t)8 * DIN + (kt),                            \
                    &sB[bufi][wave * 1024 + 512]);                          \
        gload_lds16(gB + (size_t)128 * DIN + (kt),                          \
                    &sB[bufi][8192 + wave * 1024]);                         \
        gload_lds16(gB + (size_t)136 * DIN + (kt),                          \
                    &sB[bufi][8192 + wave * 1024 + 512]);                   \
    } while (0)

#define BAR  __builtin_amdgcn_s_barrier()
#define SB0  __builtin_amdgcn_sched_barrier(0)
#define VM4  asm volatile("s_waitcnt vmcnt(4)" ::: "memory")
#define VM2  asm volatile("s_waitcnt vmcnt(2)" ::: "memory")
#define VM0  asm volatile("s_waitcnt vmcnt(0)" ::: "memory")
#define LGK4 asm volatile("s_waitcnt lgkmcnt(4)" ::: "memory")
#define LGK0 asm volatile("s_waitcnt lgkmcnt(0)" ::: "memory")

// 8 ds_read_b128: all B-frags of LDS buffer BUF (resident across its 2 phases)
#define RD_B(BUF)                                                           \
    do {                                                                    \
        _Pragma("unroll") for (int ni = 0; ni < 4; ++ni) {                  \
            bfr[ni][0] = *(const bf16x8*)&sB[BUF][rowB + ni * 1024 + q80];  \
            bfr[ni][1] = *(const bf16x8*)&sB[BUF][rowB + ni * 1024 + q81];  \
        }                                                                   \
    } while (0)

// 4 ds_read_b128: A-frags, quadrant QD of buffer BUF -> register set AF
#define RD_A(AF, BUF, QD)                                                   \
    do {                                                                    \
        _Pragma("unroll") for (int m2 = 0; m2 < 2; ++m2) {                  \
            AF[m2][0] =                                                     \
                *(const bf16x8*)&sA[BUF][rowA + ((QD)*2 + m2) * 1024 + q80];\
            AF[m2][1] =                                                     \
                *(const bf16x8*)&sA[BUF][rowA + ((QD)*2 + m2) * 1024 + q81];\
        }                                                                   \
    } while (0)

// 16 MFMA: quadrant QD from A-set AF + resident bfr
#define MM(AF, QD)                                                          \
    do {                                                                    \
        __builtin_amdgcn_s_setprio(1);                                      \
        _Pragma("unroll") for (int ks = 0; ks < 2; ++ks)                    \
            _Pragma("unroll") for (int m2 = 0; m2 < 2; ++m2)                \
                _Pragma("unroll") for (int ni = 0; ni < 4; ++ni)            \
                    acc[(QD)*2 + m2][ni] =                                  \
                        __builtin_amdgcn_mfma_f32_16x16x32_bf16(            \
                            AF[m2][ks], bfr[ni][ks],                        \
                            acc[(QD)*2 + m2][ni], 0, 0, 0);                 \
        __builtin_amdgcn_s_setprio(0);                                      \
    } while (0)

// Merged phase, first half of tile: quads 0,1 + B-burst. 16 reads, 32 MFMA.
#define PH01(BUF, STG, TAIL)                                                \
    {                                                                       \
        RD_A(af0, BUF, 0); SB0; RD_B(BUF); SB0; RD_A(af1, BUF, 1); SB0;     \
        STG;                                                                \
        TAIL;                                                               \
        BAR; LGK4; SB0; MM(af0, 0); LGK0; SB0; MM(af1, 1);                  \
    }

// Merged phase, second half of tile: quads 2,3. 8 reads, 32 MFMA.
#define PH23(BUF, STG, TAIL)                                                \
    {                                                                       \
        RD_A(af0, BUF, 2); SB0; RD_A(af1, BUF, 3); SB0;                     \
        STG;                                                                \
        TAIL;                                                               \
        BAR; LGK4; SB0; MM(af0, 2); LGK0; SB0; MM(af1, 3);                  \
    }

__global__ __launch_bounds__(512, 2) void gemm_bt(
    const unsigned short* __restrict__ A,   // [M][K] bf16
    const unsigned short* __restrict__ B,   // [N][K] bf16 (W transposed)
    float* __restrict__ C) {                // [M][N] fp32
    const int K = DIN, N = DOUT;

    __shared__ __align__(16) unsigned short sA[2][BM * BK];  // 2 x 32 KB
    __shared__ __align__(16) unsigned short sB[2][BN * BK];  // 2 x 32 KB

    const int tid  = threadIdx.x;
    const int wave = tid >> 6;
    const int lane = tid & 63;
    const int wm = wave >> 2;               // 0..1  (M)
    const int wn = wave & 3;                // 0..3  (N)

    // ---- T1: XCD-aware bijective block swizzle (512 wgs, 8 XCDs, 64/XCD) ----
    const int wg  = blockIdx.x + gridDim.x * blockIdx.y;   // hardware linear id
    const int xcd = wg & 7;
    const int idx = wg >> 3;                               // 0..63 within XCD
    const int bx  = (xcd & 1) * 8 + (idx & 7);             // 0..15  (N tiles)
    const int by  = (xcd >> 1) * 8 + (idx >> 3);           // 0..31  (M tiles)

    // ---- staging addressing: wave w stages rows 16w..16w+15 of each half ----
    const int lrow = lane >> 3;             // 0..7 row within 8-row chunk
    const int qsrc = (lane & 7) ^ lrow;     // pre-swizzled global k-quad
    const unsigned short* gA =
        A + (size_t)(by * BM + wave * 16 + lrow) * K + qsrc * 8;
    const unsigned short* gB =
        B + (size_t)(bx * BN + wave * 16 + lrow) * K + qsrc * 8;

    // ---- fragment read addressing (swizzled ds_read) ----
    const int mrow = lane & 15;
    const int kgrp = lane >> 4;             // 0..3
    const int xr   = lane & 7;              // = row&7 of the frag row
    const int q80  = ((kgrp ^ xr) << 3);        // ks=0 swizzled quad * 8
    const int q81  = (((4 | kgrp) ^ xr) << 3);  // ks=1
    const int rowA = (wm * 128 + mrow) << 6;    // *64 elems/row
    const int rowB = (wn * 64 + mrow) << 6;

    f32x4 acc[8][4];
#pragma unroll
    for (int i = 0; i < 8; ++i)
#pragma unroll
        for (int j = 0; j < 4; ++j) {
            f32x4 z = {0.f, 0.f, 0.f, 0.f};
            acc[i][j] = z;
        }
    bf16x8 bfr[4][2];     // B-frags: resident across a K-tile's 2 phases
    bf16x8 af0[2][2];     // A-frag set (even quadrant of the pair)
    bf16x8 af1[2][2];     // A-frag set (odd quadrant)

    // ---- prologue: A0, B0, B1 (12 gloads); VM4 confirms A0,B0; B1 flies ----
    STAGE_A2(0, 0);
    STAGE_B2(0, 0);
    STAGE_B2(1, 64);
    VM4;
    BAR;

    // ---- main loop: 31 iters (tiles 0..61), 4 merged phases, 1 barrier each ----
    for (int kt = 0; kt + 256 <= K; kt += 128) {
        PH01(0, STAGE_A2(1, kt + 64), )        // P0
        PH23(0, STAGE_B2(0, kt + 128), VM2)    // P1
        PH01(1, STAGE_A2(0, kt + 128), )       // P2
        PH23(1, STAGE_B2(1, kt + 192), VM2)    // P3
    }

    // ---- peeled tail: tiles 62 (buf0) and 63 (buf1) ----
    PH01(0, STAGE_A2(1, K - 64), )
    PH23(0, , VM0)        // drain A@K-64 + leftover B@K-64: buf1 confirmed
    PH01(1, , )
    PH23(1, , )

    // ---- epilogue: C/D layout col=lane&15, row=(lane>>4)*4+reg ----
    // Plain stores (R13-verified): L2 write-combines 64B halves into 128B lines.
    float* Cw = C + (size_t)(by * BM + wm * 128 + kgrp * 4) * N
                + (size_t)(bx * BN + wn * 64 + mrow);
#pragma unroll
    for (int mi = 0; mi < 8; ++mi)
#pragma unroll
        for (int ni = 0; ni < 4; ++ni)
#pragma unroll
            for (int r = 0; r < 4; ++r)
                Cw[(size_t)(mi * 16 + r) * N + ni * 16] = acc[mi][ni][r];
}

// ============ safety-net fallback if ws is too small (slow but correct) ============
__global__ void gemm_naive(const float* __restrict__ x, const int* __restrict__ W,
                           float* __restrict__ out) {
    int n = blockIdx.x * blockDim.x + threadIdx.x;
    int t = blockIdx.y;
    const float* xr = x + (size_t)t * DIN;
    float acc = 0.f;
    for (int k = 0; k < DIN; ++k)
        acc += xr[k] * (float)W[(size_t)k * DOUT + n];
    out[(size_t)t * DOUT + n] = acc;
}

extern "C" void kernel_launch(void* const* d_in, const int* in_sizes, int n_in,
                              void* d_out, int out_size, void* d_ws, size_t ws_size,
                              hipStream_t stream) {
    const float* x = (const float*)d_in[0];
    const int*   W = (const int*)d_in[1];
    float* out = (float*)d_out;

    const size_t xb_elems = (size_t)TOKENS * DIN;           // 64 MB bf16
    const size_t wt_elems = (size_t)DIN * DOUT;             // 32 MB bf16
    const size_t need = (xb_elems + wt_elems) * sizeof(unsigned short);

    if (ws_size < need) {   // should not happen; correctness safety net
        dim3 g(DOUT / 256, TOKENS);
        gemm_naive<<<g, 256, 0, stream>>>(x, W, out);
        return;
    }

    unsigned short* xb = (unsigned short*)d_ws;
    unsigned short* Wt = xb + xb_elems;

    fused_cvt<<<WBLKS + XBLKS, 256, 0, stream>>>(x, W, xb, Wt);

    dim3 grid(DOUT / BN, TOKENS / BM);   // (16, 32)
    gemm_bt<<<grid, 512, 0, stream>>>(xb, Wt, out);
}